// Round 1
// 601.450 us; speedup vs baseline: 1.0163x; 1.0163x over previous
//
#include <hip/hip_runtime.h>

#define N_PTS 1048576
#define B_SEG 4096
#define LN_EPS 1e-5f

__device__ __forceinline__ int lower_bound_i(const int* __restrict__ a, int n, int v){
  int lo = 0, hi = n;
  while(lo < hi){
    int m = (lo + hi) >> 1;
    if(a[m] < v) lo = m + 1; else hi = m;
  }
  return lo;
}

__device__ __forceinline__ float f4e(const float4& v, int j){
  return j==0 ? v.x : j==1 ? v.y : j==2 ? v.z : v.w;
}

// ---------------- Single fused kernel ----------------
// grid = 1024 blocks (4 samples each), block = 256 threads.
// Phase 1: segment mean-pool the block's 4 segments (streaming, 240/256 lanes active).
// Phase 2: coarse + routed refinement MLPs entirely in LDS. No global scratch.
__global__ __launch_bounds__(256, 4) void fused_kernel(
    const float* __restrict__ feat, const int* __restrict__ seg,
    const int* __restrict__ class_ids,
    const float* __restrict__ cW1, const float* __restrict__ cb1,
    const float* __restrict__ cg1, const float* __restrict__ cbe1,
    const float* __restrict__ cW2, const float* __restrict__ cb2,
    const float* __restrict__ cg2, const float* __restrict__ cbe2,
    const float* __restrict__ cW3, const float* __restrict__ cb3,
    const float* __restrict__ rW1, const float* __restrict__ rb1,
    const float* __restrict__ rg1, const float* __restrict__ rbe1,
    const float* __restrict__ rW2, const float* __restrict__ rb2,
    const float* __restrict__ rg2, const float* __restrict__ rbe2,
    const float* __restrict__ rW3, const float* __restrict__ rb3,
    float* __restrict__ out)
{
  const int tid  = threadIdx.x;
  const int b0   = blockIdx.x * 4;
  const int lane = tid & 63;
  const int wv   = tid >> 6;

  __shared__ int    bnd[5];
  __shared__ int    kcls[4];
  __shared__ float4 part[960];                    // 4 segs x 10 rows x 24 groups
  __shared__ __align__(16) float p  [4*96];
  __shared__ __align__(16) float h1 [4*256];
  __shared__ float h2 [4*132];                    // padded stride 132
  __shared__ __align__(16) float r1b[4*128];
  __shared__ float r2b[4*68];                     // padded stride 68
  __shared__ float couts[12];
  __shared__ float redbuf[4][32];
  __shared__ float stats[32];

  if(tid < 5)              bnd[tid]      = lower_bound_i(seg, N_PTS, b0 + tid);
  if(tid >= 8 && tid < 12) kcls[tid - 8] = class_ids[b0 + tid - 8];
  __syncthreads();

  //======== Phase 1: segment mean pooling (4 segments) ========
  {
    const int g = tid % 24;           // float4 group within the 96-ch row
    const int r = tid / 24;           // row phase 0..9 (tid>=240 idle)
    const int e0 = bnd[0], e1 = bnd[1], e2 = bnd[2], e3 = bnd[3], e4 = bnd[4];
    const float4* __restrict__ f4 = (const float4*)feat;
    if(r < 10){
      float4 a0 = make_float4(0.f,0.f,0.f,0.f), a1 = a0, a2 = a0, a3 = a0;
      for(int row = e0 + r; row < e1; row += 10){
        float4 v = f4[(size_t)row*24 + g];
        a0.x += v.x; a0.y += v.y; a0.z += v.z; a0.w += v.w;
      }
      for(int row = e1 + r; row < e2; row += 10){
        float4 v = f4[(size_t)row*24 + g];
        a1.x += v.x; a1.y += v.y; a1.z += v.z; a1.w += v.w;
      }
      for(int row = e2 + r; row < e3; row += 10){
        float4 v = f4[(size_t)row*24 + g];
        a2.x += v.x; a2.y += v.y; a2.z += v.z; a2.w += v.w;
      }
      for(int row = e3 + r; row < e4; row += 10){
        float4 v = f4[(size_t)row*24 + g];
        a3.x += v.x; a3.y += v.y; a3.z += v.z; a3.w += v.w;
      }
      part[      tid] = a0;
      part[240 + tid] = a1;
      part[480 + tid] = a2;
      part[720 + tid] = a3;
    }
    __syncthreads();
    if(tid < 96){
      const int s = tid / 24, gc = tid % 24;
      float sx=0.f, sy=0.f, sz=0.f, sw=0.f;
      #pragma unroll
      for(int rr=0; rr<10; rr++){
        float4 v = part[s*240 + rr*24 + gc];
        sx += v.x; sy += v.y; sz += v.z; sw += v.w;
      }
      int cnt = bnd[s+1] - bnd[s]; if(cnt < 1) cnt = 1;
      float inv = 1.f / (float)cnt;
      ((float4*)p)[s*24 + gc] = make_float4(sx*inv, sy*inv, sz*inv, sw*inv);
    }
    __syncthreads();
  }

  //======== coarse L1: 96 -> 256, LN, ReLU ========
  {
    const int o = tid;                 // output channel
    float acc[4];
    float bias = cb1[o];
    #pragma unroll
    for(int s=0;s<4;s++) acc[s] = bias;
    for(int c0=0;c0<96;c0+=4){
      float4 pv[4];
      #pragma unroll
      for(int s=0;s<4;s++) pv[s] = *(const float4*)&p[s*96 + c0];
      #pragma unroll
      for(int j=0;j<4;j++){
        float w = cW1[(c0+j)*256 + o];
        #pragma unroll
        for(int s=0;s<4;s++) acc[s] = fmaf(f4e(pv[s], j), w, acc[s]);
      }
    }
    float sum[4], sq[4];
    #pragma unroll
    for(int s=0;s<4;s++){ sum[s]=acc[s]; sq[s]=acc[s]*acc[s]; }
    #pragma unroll
    for(int m=32;m>=1;m>>=1){
      #pragma unroll
      for(int s=0;s<4;s++){
        sum[s] += __shfl_xor(sum[s], m, 64);
        sq[s]  += __shfl_xor(sq[s],  m, 64);
      }
    }
    if(lane == 0){
      #pragma unroll
      for(int s=0;s<4;s++){ redbuf[wv][s]=sum[s]; redbuf[wv][8+s]=sq[s]; }
    }
    __syncthreads();
    if(tid < 16) stats[tid] = redbuf[0][tid]+redbuf[1][tid]+redbuf[2][tid]+redbuf[3][tid];
    __syncthreads();
    float gg = cg1[o], be = cbe1[o];
    #pragma unroll
    for(int s=0;s<4;s++){
      float mean = stats[s]   * (1.f/256.f);
      float var  = stats[8+s] * (1.f/256.f) - mean*mean;
      float rstd = rsqrtf(var + LN_EPS);
      float v = (acc[s]-mean)*rstd*gg + be;
      h1[s*256 + o] = v > 0.f ? v : 0.f;
    }
    __syncthreads();
  }

  //======== coarse L2: 256 -> 128, LN, ReLU ========
  {
    const int o = tid & 127;
    const int g = tid >> 7;            // 0..1 : samples g*2, g*2+1
    float acc[2];
    float bias = cb2[o];
    #pragma unroll
    for(int s=0;s<2;s++) acc[s] = bias;
    for(int c0=0;c0<256;c0+=4){
      float4 hv[2];
      #pragma unroll
      for(int s=0;s<2;s++) hv[s] = *(const float4*)&h1[(g*2+s)*256 + c0];
      #pragma unroll
      for(int j=0;j<4;j++){
        float w = cW2[(c0+j)*128 + o];
        #pragma unroll
        for(int s=0;s<2;s++) acc[s] = fmaf(f4e(hv[s], j), w, acc[s]);
      }
    }
    float sum[2], sq[2];
    #pragma unroll
    for(int s=0;s<2;s++){ sum[s]=acc[s]; sq[s]=acc[s]*acc[s]; }
    #pragma unroll
    for(int m=32;m>=1;m>>=1){
      #pragma unroll
      for(int s=0;s<2;s++){
        sum[s] += __shfl_xor(sum[s], m, 64);
        sq[s]  += __shfl_xor(sq[s],  m, 64);
      }
    }
    if(lane == 0){
      #pragma unroll
      for(int s=0;s<2;s++){ redbuf[wv][s]=sum[s]; redbuf[wv][2+s]=sq[s]; }
    }
    __syncthreads();
    if(tid < 8){ int gq = tid>>2, i = tid&3; stats[tid] = redbuf[2*gq][i] + redbuf[2*gq+1][i]; }
    __syncthreads();
    float gg = cg2[o], be = cbe2[o];
    #pragma unroll
    for(int s=0;s<2;s++){
      float mean = stats[g*4+s]   * (1.f/128.f);
      float var  = stats[g*4+2+s] * (1.f/128.f) - mean*mean;
      float rstd = rsqrtf(var + LN_EPS);
      float v = (acc[s]-mean)*rstd*gg + be;
      h2[(g*2+s)*132 + o] = v > 0.f ? v : 0.f;
    }
    __syncthreads();
  }

  //======== coarse L3: 128 -> 3 (no sync inside) ========
  if(tid < 12){
    int s = tid/3, j = tid - 3*(tid/3);
    float a = cb3[j];
    for(int c=0;c<128;c++) a = fmaf(h2[s*132 + c], cW3[c*3 + j], a);
    couts[tid] = a;
  }

  //======== refine L1 (routed): 96 -> 128, LN, ReLU ========
  {
    const int o = tid & 127;
    const int g = tid >> 7;            // 0..1 : samples g*2, g*2+1
    int ks[2]; const float* wp[2]; float acc[2];
    #pragma unroll
    for(int s=0;s<2;s++){
      ks[s]  = kcls[g*2+s];
      wp[s]  = rW1 + ks[s]*(96*128) + o;
      acc[s] = rb1[ks[s]*128 + o];
    }
    for(int c0=0;c0<96;c0+=4){
      float4 pv[2];
      #pragma unroll
      for(int s=0;s<2;s++) pv[s] = *(const float4*)&p[(g*2+s)*96 + c0];
      #pragma unroll
      for(int j=0;j<4;j++){
        #pragma unroll
        for(int s=0;s<2;s++){
          float w = wp[s][(c0+j)*128];
          acc[s] = fmaf(f4e(pv[s], j), w, acc[s]);
        }
      }
    }
    float sum[2], sq[2];
    #pragma unroll
    for(int s=0;s<2;s++){ sum[s]=acc[s]; sq[s]=acc[s]*acc[s]; }
    #pragma unroll
    for(int m=32;m>=1;m>>=1){
      #pragma unroll
      for(int s=0;s<2;s++){
        sum[s] += __shfl_xor(sum[s], m, 64);
        sq[s]  += __shfl_xor(sq[s],  m, 64);
      }
    }
    if(lane == 0){
      #pragma unroll
      for(int s=0;s<2;s++){ redbuf[wv][s]=sum[s]; redbuf[wv][2+s]=sq[s]; }
    }
    __syncthreads();
    if(tid < 8){ int gq = tid>>2, i = tid&3; stats[tid] = redbuf[2*gq][i] + redbuf[2*gq+1][i]; }
    __syncthreads();
    #pragma unroll
    for(int s=0;s<2;s++){
      float mean = stats[g*4+s]   * (1.f/128.f);
      float var  = stats[g*4+2+s] * (1.f/128.f) - mean*mean;
      float rstd = rsqrtf(var + LN_EPS);
      float v = (acc[s]-mean)*rstd*rg1[ks[s]*128+o] + rbe1[ks[s]*128+o];
      r1b[(g*2+s)*128 + o] = v > 0.f ? v : 0.f;
    }
    __syncthreads();
  }

  //======== refine L2 (routed): 128 -> 64, LN, ReLU — one sample per wave ========
  {
    const int o = tid & 63;
    const int g = wv;                  // 0..3 : sample g
    const int k = kcls[g];
    float acc = rb2[k*64 + o];
    const float* wp = rW2 + k*(128*64) + o;
    for(int c0=0;c0<128;c0+=4){
      float4 rv = *(const float4*)&r1b[g*128 + c0];
      #pragma unroll
      for(int j=0;j<4;j++) acc = fmaf(f4e(rv, j), wp[(c0+j)*64], acc);
    }
    float sum = acc, sq = acc*acc;
    #pragma unroll
    for(int m=32;m>=1;m>>=1){
      sum += __shfl_xor(sum, m, 64);
      sq  += __shfl_xor(sq,  m, 64);
    }
    float mean = sum * (1.f/64.f);
    float var  = sq  * (1.f/64.f) - mean*mean;
    float rstd = rsqrtf(var + LN_EPS);
    float v = (acc-mean)*rstd*rg2[k*64+o] + rbe2[k*64+o];
    r2b[g*68 + o] = v > 0.f ? v : 0.f;
    __syncthreads();
  }

  //======== refine L3 + combine ========
  if(tid < 12){
    int s = tid/3, j = tid - 3*(tid/3);
    int k = kcls[s];
    float a = rb3[k*3 + j];
    const float* w = rW3 + k*192 + j;
    for(int c=0;c<64;c++) a = fmaf(r2b[s*68 + c], w[c*3], a);
    out[(b0+s)*3 + j] = a + couts[tid];
  }
}

extern "C" void kernel_launch(void* const* d_in, const int* in_sizes, int n_in,
                              void* d_out, int out_size, void* d_ws, size_t ws_size,
                              hipStream_t stream)
{
  const float* feat = (const float*)d_in[0];
  const int*   seg  = (const int*)d_in[1];
  const int*   cls  = (const int*)d_in[2];
  const float* cW1  = (const float*)d_in[3];
  const float* cb1  = (const float*)d_in[4];
  const float* cg1  = (const float*)d_in[5];
  const float* cbe1 = (const float*)d_in[6];
  const float* cW2  = (const float*)d_in[7];
  const float* cb2  = (const float*)d_in[8];
  const float* cg2  = (const float*)d_in[9];
  const float* cbe2 = (const float*)d_in[10];
  const float* cW3  = (const float*)d_in[11];
  const float* cb3  = (const float*)d_in[12];
  const float* rW1  = (const float*)d_in[13];
  const float* rb1  = (const float*)d_in[14];
  const float* rg1  = (const float*)d_in[15];
  const float* rbe1 = (const float*)d_in[16];
  const float* rW2  = (const float*)d_in[17];
  const float* rb2  = (const float*)d_in[18];
  const float* rg2  = (const float*)d_in[19];
  const float* rbe2 = (const float*)d_in[20];
  const float* rW3  = (const float*)d_in[21];
  const float* rb3  = (const float*)d_in[22];
  float* out = (float*)d_out;
  // NOTE: d_ws intentionally unused — everything lives in LDS now.
  (void)d_ws; (void)ws_size;

  fused_kernel<<<B_SEG/4, 256, 0, stream>>>(feat, seg, cls,
      cW1, cb1, cg1, cbe1, cW2, cb2, cg2, cbe2, cW3, cb3,
      rW1, rb1, rg1, rbe1, rW2, rb2, rg2, rbe2, rW3, rb3, out);
}

// Round 2
// 588.715 us; speedup vs baseline: 1.0383x; 1.0216x over previous
//
#include <hip/hip_runtime.h>

#define N_PTS 1048576
#define B_SEG 4096
#define LN_EPS 1e-5f

__device__ __forceinline__ float f4e(const float4& v, int j){
  return j==0 ? v.x : j==1 ? v.y : j==2 ? v.z : v.w;
}

// ---------------- Kernel 0: segment boundary precompute ----------------
// bnd[b] = lower_bound(seg, b) for b in [0, 4096]. Sorted input -> each bnd[b]
// is written by exactly one thread (the unique i with seg[i-1] < b <= seg[i]).
__global__ __launch_bounds__(256) void bounds_kernel(
    const int* __restrict__ seg, int* __restrict__ bnd)
{
  int i = blockIdx.x * blockDim.x + threadIdx.x;
  const int stride = gridDim.x * blockDim.x;
  for(; i < N_PTS; i += stride){
    const int cur  = seg[i];
    const int prev = (i == 0) ? -1 : seg[i-1];
    for(int b = prev + 1; b <= cur; ++b) bnd[b] = i;
    if(i == N_PTS - 1){
      for(int b = cur + 1; b <= B_SEG; ++b) bnd[b] = N_PTS;
    }
  }
}

// ---------------- Kernel 1: fused pool + MLP ----------------
// grid = 1024 blocks (4 samples each), block = 256 threads, fully resident (4 blk/CU).
__global__ __launch_bounds__(256, 4) void fused_kernel(
    const float* __restrict__ feat, const int* __restrict__ bndg,
    const int* __restrict__ class_ids,
    const float* __restrict__ cW1, const float* __restrict__ cb1,
    const float* __restrict__ cg1, const float* __restrict__ cbe1,
    const float* __restrict__ cW2, const float* __restrict__ cb2,
    const float* __restrict__ cg2, const float* __restrict__ cbe2,
    const float* __restrict__ cW3, const float* __restrict__ cb3,
    const float* __restrict__ rW1, const float* __restrict__ rb1,
    const float* __restrict__ rg1, const float* __restrict__ rbe1,
    const float* __restrict__ rW2, const float* __restrict__ rb2,
    const float* __restrict__ rg2, const float* __restrict__ rbe2,
    const float* __restrict__ rW3, const float* __restrict__ rb3,
    float* __restrict__ out)
{
  const int tid  = threadIdx.x;
  const int b0   = blockIdx.x * 4;
  const int lane = tid & 63;
  const int wv   = tid >> 6;

  __shared__ int    bnd[5];
  __shared__ int    kcls[4];
  __shared__ float4 part[960];                    // 4 segs x 10 rows x 24 groups
  __shared__ __align__(16) float p  [4*96];
  __shared__ __align__(16) float h1 [4*256];
  __shared__ float h2 [4*132];                    // padded stride 132
  __shared__ __align__(16) float r1b[4*128];
  __shared__ float r2b[4*68];                     // padded stride 68
  __shared__ float couts[12];
  __shared__ float redbuf[4][32];
  __shared__ float stats[32];

  if(tid < 5)              bnd[tid]      = bndg[b0 + tid];          // precomputed
  if(tid >= 8 && tid < 12) kcls[tid - 8] = class_ids[b0 + tid - 8];
  __syncthreads();

  //======== Phase 1: segment mean pooling (4 segments) ========
  {
    const int g = tid % 24;           // float4 group within the 96-ch row
    const int r = tid / 24;           // row phase 0..9 (tid>=240 idle)
    const int e0 = bnd[0], e1 = bnd[1], e2 = bnd[2], e3 = bnd[3], e4 = bnd[4];
    const float4* __restrict__ f4 = (const float4*)feat;
    if(r < 10){
      float4 s0, s1, s2, s3;
      // dual-stream accumulation: 2 independent loads in flight per iter
      #define POOL_SEG(E0, E1, OUTV)                                          \
      {                                                                       \
        float4 aA = make_float4(0.f,0.f,0.f,0.f), aB = aA;                    \
        int row = (E0) + r;                                                   \
        for(; row + 10 < (E1); row += 20){                                    \
          float4 u = f4[(size_t)row*24 + g];                                  \
          float4 v = f4[(size_t)(row+10)*24 + g];                             \
          aA.x += u.x; aA.y += u.y; aA.z += u.z; aA.w += u.w;                 \
          aB.x += v.x; aB.y += v.y; aB.z += v.z; aB.w += v.w;                 \
        }                                                                     \
        if(row < (E1)){                                                       \
          float4 u = f4[(size_t)row*24 + g];                                  \
          aA.x += u.x; aA.y += u.y; aA.z += u.z; aA.w += u.w;                 \
        }                                                                     \
        OUTV = make_float4(aA.x+aB.x, aA.y+aB.y, aA.z+aB.z, aA.w+aB.w);       \
      }
      POOL_SEG(e0, e1, s0)
      POOL_SEG(e1, e2, s1)
      POOL_SEG(e2, e3, s2)
      POOL_SEG(e3, e4, s3)
      #undef POOL_SEG
      part[      tid] = s0;
      part[240 + tid] = s1;
      part[480 + tid] = s2;
      part[720 + tid] = s3;
    }
    __syncthreads();
    if(tid < 96){
      const int s = tid / 24, gc = tid % 24;
      float sx=0.f, sy=0.f, sz=0.f, sw=0.f;
      #pragma unroll
      for(int rr=0; rr<10; rr++){
        float4 v = part[s*240 + rr*24 + gc];
        sx += v.x; sy += v.y; sz += v.z; sw += v.w;
      }
      int cnt = bnd[s+1] - bnd[s]; if(cnt < 1) cnt = 1;
      float inv = 1.f / (float)cnt;
      ((float4*)p)[s*24 + gc] = make_float4(sx*inv, sy*inv, sz*inv, sw*inv);
    }
    __syncthreads();
  }

  //======== coarse L1: 96 -> 256, LN, ReLU ========
  {
    const int o = tid;                 // output channel
    float acc[4];
    float bias = cb1[o];
    #pragma unroll
    for(int s=0;s<4;s++) acc[s] = bias;
    for(int c0=0;c0<96;c0+=4){
      float4 pv[4];
      #pragma unroll
      for(int s=0;s<4;s++) pv[s] = *(const float4*)&p[s*96 + c0];
      #pragma unroll
      for(int j=0;j<4;j++){
        float w = cW1[(c0+j)*256 + o];
        #pragma unroll
        for(int s=0;s<4;s++) acc[s] = fmaf(f4e(pv[s], j), w, acc[s]);
      }
    }
    float sum[4], sq[4];
    #pragma unroll
    for(int s=0;s<4;s++){ sum[s]=acc[s]; sq[s]=acc[s]*acc[s]; }
    #pragma unroll
    for(int m=32;m>=1;m>>=1){
      #pragma unroll
      for(int s=0;s<4;s++){
        sum[s] += __shfl_xor(sum[s], m, 64);
        sq[s]  += __shfl_xor(sq[s],  m, 64);
      }
    }
    if(lane == 0){
      #pragma unroll
      for(int s=0;s<4;s++){ redbuf[wv][s]=sum[s]; redbuf[wv][8+s]=sq[s]; }
    }
    __syncthreads();
    if(tid < 16) stats[tid] = redbuf[0][tid]+redbuf[1][tid]+redbuf[2][tid]+redbuf[3][tid];
    __syncthreads();
    float gg = cg1[o], be = cbe1[o];
    #pragma unroll
    for(int s=0;s<4;s++){
      float mean = stats[s]   * (1.f/256.f);
      float var  = stats[8+s] * (1.f/256.f) - mean*mean;
      float rstd = rsqrtf(var + LN_EPS);
      float v = (acc[s]-mean)*rstd*gg + be;
      h1[s*256 + o] = v > 0.f ? v : 0.f;
    }
    __syncthreads();
  }

  //======== coarse L2: 256 -> 128, LN, ReLU ========
  {
    const int o = tid & 127;
    const int g = tid >> 7;            // 0..1 : samples g*2, g*2+1
    float acc[2];
    float bias = cb2[o];
    #pragma unroll
    for(int s=0;s<2;s++) acc[s] = bias;
    for(int c0=0;c0<256;c0+=4){
      float4 hv[2];
      #pragma unroll
      for(int s=0;s<2;s++) hv[s] = *(const float4*)&h1[(g*2+s)*256 + c0];
      #pragma unroll
      for(int j=0;j<4;j++){
        float w = cW2[(c0+j)*128 + o];
        #pragma unroll
        for(int s=0;s<2;s++) acc[s] = fmaf(f4e(hv[s], j), w, acc[s]);
      }
    }
    float sum[2], sq[2];
    #pragma unroll
    for(int s=0;s<2;s++){ sum[s]=acc[s]; sq[s]=acc[s]*acc[s]; }
    #pragma unroll
    for(int m=32;m>=1;m>>=1){
      #pragma unroll
      for(int s=0;s<2;s++){
        sum[s] += __shfl_xor(sum[s], m, 64);
        sq[s]  += __shfl_xor(sq[s],  m, 64);
      }
    }
    if(lane == 0){
      #pragma unroll
      for(int s=0;s<2;s++){ redbuf[wv][s]=sum[s]; redbuf[wv][2+s]=sq[s]; }
    }
    __syncthreads();
    if(tid < 8){ int gq = tid>>2, i = tid&3; stats[tid] = redbuf[2*gq][i] + redbuf[2*gq+1][i]; }
    __syncthreads();
    float gg = cg2[o], be = cbe2[o];
    #pragma unroll
    for(int s=0;s<2;s++){
      float mean = stats[g*4+s]   * (1.f/128.f);
      float var  = stats[g*4+2+s] * (1.f/128.f) - mean*mean;
      float rstd = rsqrtf(var + LN_EPS);
      float v = (acc[s]-mean)*rstd*gg + be;
      h2[(g*2+s)*132 + o] = v > 0.f ? v : 0.f;
    }
    __syncthreads();
  }

  //======== coarse L3: 128 -> 3 (no sync inside) ========
  if(tid < 12){
    int s = tid/3, j = tid - 3*(tid/3);
    float a = cb3[j];
    for(int c=0;c<128;c++) a = fmaf(h2[s*132 + c], cW3[c*3 + j], a);
    couts[tid] = a;
  }

  //======== refine L1 (routed): 96 -> 128, LN, ReLU ========
  {
    const int o = tid & 127;
    const int g = tid >> 7;            // 0..1 : samples g*2, g*2+1
    int ks[2]; const float* wp[2]; float acc[2];
    #pragma unroll
    for(int s=0;s<2;s++){
      ks[s]  = kcls[g*2+s];
      wp[s]  = rW1 + ks[s]*(96*128) + o;
      acc[s] = rb1[ks[s]*128 + o];
    }
    for(int c0=0;c0<96;c0+=4){
      float4 pv[2];
      #pragma unroll
      for(int s=0;s<2;s++) pv[s] = *(const float4*)&p[(g*2+s)*96 + c0];
      #pragma unroll
      for(int j=0;j<4;j++){
        #pragma unroll
        for(int s=0;s<2;s++){
          float w = wp[s][(c0+j)*128];
          acc[s] = fmaf(f4e(pv[s], j), w, acc[s]);
        }
      }
    }
    float sum[2], sq[2];
    #pragma unroll
    for(int s=0;s<2;s++){ sum[s]=acc[s]; sq[s]=acc[s]*acc[s]; }
    #pragma unroll
    for(int m=32;m>=1;m>>=1){
      #pragma unroll
      for(int s=0;s<2;s++){
        sum[s] += __shfl_xor(sum[s], m, 64);
        sq[s]  += __shfl_xor(sq[s],  m, 64);
      }
    }
    if(lane == 0){
      #pragma unroll
      for(int s=0;s<2;s++){ redbuf[wv][s]=sum[s]; redbuf[wv][2+s]=sq[s]; }
    }
    __syncthreads();
    if(tid < 8){ int gq = tid>>2, i = tid&3; stats[tid] = redbuf[2*gq][i] + redbuf[2*gq+1][i]; }
    __syncthreads();
    #pragma unroll
    for(int s=0;s<2;s++){
      float mean = stats[g*4+s]   * (1.f/128.f);
      float var  = stats[g*4+2+s] * (1.f/128.f) - mean*mean;
      float rstd = rsqrtf(var + LN_EPS);
      float v = (acc[s]-mean)*rstd*rg1[ks[s]*128+o] + rbe1[ks[s]*128+o];
      r1b[(g*2+s)*128 + o] = v > 0.f ? v : 0.f;
    }
    __syncthreads();
  }

  //======== refine L2 (routed): 128 -> 64, LN, ReLU — one sample per wave ========
  {
    const int o = tid & 63;
    const int g = wv;                  // 0..3 : sample g
    const int k = kcls[g];
    float acc = rb2[k*64 + o];
    const float* wp = rW2 + k*(128*64) + o;
    for(int c0=0;c0<128;c0+=4){
      float4 rv = *(const float4*)&r1b[g*128 + c0];
      #pragma unroll
      for(int j=0;j<4;j++) acc = fmaf(f4e(rv, j), wp[(c0+j)*64], acc);
    }
    float sum = acc, sq = acc*acc;
    #pragma unroll
    for(int m=32;m>=1;m>>=1){
      sum += __shfl_xor(sum, m, 64);
      sq  += __shfl_xor(sq,  m, 64);
    }
    float mean = sum * (1.f/64.f);
    float var  = sq  * (1.f/64.f) - mean*mean;
    float rstd = rsqrtf(var + LN_EPS);
    float v = (acc-mean)*rstd*rg2[k*64+o] + rbe2[k*64+o];
    r2b[g*68 + o] = v > 0.f ? v : 0.f;
    __syncthreads();
  }

  //======== refine L3 + combine ========
  if(tid < 12){
    int s = tid/3, j = tid - 3*(tid/3);
    int k = kcls[s];
    float a = rb3[k*3 + j];
    const float* w = rW3 + k*192 + j;
    for(int c=0;c<64;c++) a = fmaf(r2b[s*68 + c], w[c*3], a);
    out[(b0+s)*3 + j] = a + couts[tid];
  }
}

extern "C" void kernel_launch(void* const* d_in, const int* in_sizes, int n_in,
                              void* d_out, int out_size, void* d_ws, size_t ws_size,
                              hipStream_t stream)
{
  const float* feat = (const float*)d_in[0];
  const int*   seg  = (const int*)d_in[1];
  const int*   cls  = (const int*)d_in[2];
  const float* cW1  = (const float*)d_in[3];
  const float* cb1  = (const float*)d_in[4];
  const float* cg1  = (const float*)d_in[5];
  const float* cbe1 = (const float*)d_in[6];
  const float* cW2  = (const float*)d_in[7];
  const float* cb2  = (const float*)d_in[8];
  const float* cg2  = (const float*)d_in[9];
  const float* cbe2 = (const float*)d_in[10];
  const float* cW3  = (const float*)d_in[11];
  const float* cb3  = (const float*)d_in[12];
  const float* rW1  = (const float*)d_in[13];
  const float* rb1  = (const float*)d_in[14];
  const float* rg1  = (const float*)d_in[15];
  const float* rbe1 = (const float*)d_in[16];
  const float* rW2  = (const float*)d_in[17];
  const float* rb2  = (const float*)d_in[18];
  const float* rg2  = (const float*)d_in[19];
  const float* rbe2 = (const float*)d_in[20];
  const float* rW3  = (const float*)d_in[21];
  const float* rb3  = (const float*)d_in[22];
  float* out = (float*)d_out;
  int* bnd = (int*)d_ws;   // 4097 ints — poison fill happens regardless, so ws use is free

  bounds_kernel<<<1024, 256, 0, stream>>>(seg, bnd);
  fused_kernel<<<B_SEG/4, 256, 0, stream>>>(feat, bnd, cls,
      cW1, cb1, cg1, cbe1, cW2, cb2, cg2, cbe2, cW3, cb3,
      rW1, rb1, rg1, rbe1, rW2, rb2, rg2, rbe2, rW3, rb3, out);
}